// Round 1
// baseline (29359.024 us; speedup 1.0000x reference)
//
#include <hip/hip_runtime.h>

#define T_SEQ 512
#define NBATCH 2048
#define HID 64
#define NIN 20

// workspace float offsets
#define ST_H0 0
#define ST_C0 (NBATCH * HID)
#define ST_H1 (2 * NBATCH * HID)
#define ST_C1 (3 * NBATCH * HID)
#define Y0_OFF (4 * NBATCH * HID)

__device__ __forceinline__ float bcastf(float v, int l) {
  return __uint_as_float((unsigned)__builtin_amdgcn_readlane((int)__float_as_uint(v), l));
}
__device__ __forceinline__ float sigm(float v) {
  return __builtin_amdgcn_rcpf(1.0f + __expf(-v));
}
__device__ __forceinline__ float ftanh(float v) {
  const float a = fabsf(v);
  const float e = __expf(-2.0f * a);
  const float r = (1.0f - e) * __builtin_amdgcn_rcpf(1.0f + e);
  return copysignf(r, v);
}

// Layer 0: weights fully register-resident (80 + 256 VGPR/lane), R=2 batches/wave.
// lane u owns hidden unit u (gate rows u, 64+u, 128+u, 192+u).
__global__ __launch_bounds__(256, 1) void lstm_layer0(
    const float* __restrict__ x, const float* __restrict__ w_ih,
    const float* __restrict__ w_hh, const float* __restrict__ b_ih,
    const float* __restrict__ b_hh, float* __restrict__ ws, int t0, int Tc) {
  const int lane = threadIdx.x & 63;
  // force wave-uniform so x row pointers become scalar (s_load) addresses
  const int wid = __builtin_amdgcn_readfirstlane((int)(blockIdx.x * 4) + (int)(threadIdx.x >> 6));
  const int b0 = wid * 2;
  const int b1 = b0 + 1;
  float* __restrict__ y0 = ws + Y0_OFF;

  float wi[4][NIN];
  float wh[4][HID];
  float bias[4];
#pragma unroll
  for (int g = 0; g < 4; ++g) {
    const int row = g * HID + lane;
    const float* wip = w_ih + row * NIN;
    const float* whp = w_hh + row * HID;
#pragma unroll
    for (int k = 0; k < NIN; ++k) wi[g][k] = wip[k];
#pragma unroll
    for (int k = 0; k < HID; ++k) wh[g][k] = whp[k];
    bias[g] = b_ih[row] + b_hh[row];
  }

  float h0, h1, c0, c1;
  if (t0 == 0) {
    h0 = h1 = c0 = c1 = 0.0f;
  } else {
    h0 = ws[ST_H0 + b0 * HID + lane];
    h1 = ws[ST_H0 + b1 * HID + lane];
    c0 = ws[ST_C0 + b0 * HID + lane];
    c1 = ws[ST_C0 + b1 * HID + lane];
  }

#pragma unroll 1
  for (int tt = 0; tt < Tc; ++tt) {
    const int t = t0 + tt;
    const float* __restrict__ xp0 = x + ((size_t)b0 * T_SEQ + t) * NIN;
    const float* __restrict__ xp1 = x + ((size_t)b1 * T_SEQ + t) * NIN;
    float xv0[NIN], xv1[NIN];
#pragma unroll
    for (int k = 0; k < NIN; ++k) { xv0[k] = xp0[k]; xv1[k] = xp1[k]; }

    float a0[4], a1[4];
#pragma unroll
    for (int g = 0; g < 4; ++g) { a0[g] = bias[g]; a1[g] = bias[g]; }

    // recurrent part first (hides x-load latency); h broadcast via v_readlane
#pragma unroll
    for (int k = 0; k < HID; ++k) {
      const float hk0 = bcastf(h0, k);
      const float hk1 = bcastf(h1, k);
#pragma unroll
      for (int g = 0; g < 4; ++g) {
        a0[g] = fmaf(wh[g][k], hk0, a0[g]);
        a1[g] = fmaf(wh[g][k], hk1, a1[g]);
      }
    }
#pragma unroll
    for (int k = 0; k < NIN; ++k) {
#pragma unroll
      for (int g = 0; g < 4; ++g) {
        a0[g] = fmaf(wi[g][k], xv0[k], a0[g]);
        a1[g] = fmaf(wi[g][k], xv1[k], a1[g]);
      }
    }

    {
      const float ig = sigm(a0[0]), fg = sigm(a0[1]), gv = ftanh(a0[2]), og = sigm(a0[3]);
      c0 = fg * c0 + ig * gv;
      h0 = og * ftanh(c0);
      y0[((size_t)b0 * Tc + tt) * HID + lane] = h0;
    }
    {
      const float ig = sigm(a1[0]), fg = sigm(a1[1]), gv = ftanh(a1[2]), og = sigm(a1[3]);
      c1 = fg * c1 + ig * gv;
      h1 = og * ftanh(c1);
      y0[((size_t)b1 * Tc + tt) * HID + lane] = h1;
    }
  }

  ws[ST_H0 + b0 * HID + lane] = h0;
  ws[ST_H0 + b1 * HID + lane] = h1;
  ws[ST_C0 + b0 * HID + lane] = c0;
  ws[ST_C0 + b1 * HID + lane] = c1;
}

// Layer 1: W_hh1 register-resident (256 VGPR/lane), W_ih1 in LDS (64 KB) laid out
// [k][unit][gate] so each lane reads one float4 (ds_read_b128) per k. Fuses the
// final projection out = h_last @ w_out^T + b_out on the last chunk.
__global__ __launch_bounds__(256, 1) void lstm_layer1(
    const float* __restrict__ w_ih, const float* __restrict__ w_hh,
    const float* __restrict__ b_ih, const float* __restrict__ b_hh,
    const float* __restrict__ w_out, const float* __restrict__ b_out,
    float* __restrict__ out, float* __restrict__ ws, int t0, int Tc) {
  __shared__ float wlds[256 * HID];  // [k][unit][gate], 64 KB
  const int lane = threadIdx.x & 63;
  const int wid = __builtin_amdgcn_readfirstlane((int)(blockIdx.x * 4) + (int)(threadIdx.x >> 6));
  const int b0 = wid * 2;
  const int b1 = b0 + 1;
  const float* __restrict__ y0 = ws + Y0_OFF;

  for (int e = threadIdx.x; e < 256 * HID; e += 256) {
    const int row = e >> 6;       // gate-row 0..255
    const int k = e & (HID - 1);  // 0..63
    const int g = row >> 6;       // gate 0..3
    const int uu = row & 63;      // unit
    wlds[(k * 64 + uu) * 4 + g] = w_ih[e];
  }

  float wh[4][HID], bias[4];
#pragma unroll
  for (int g = 0; g < 4; ++g) {
    const int row = g * HID + lane;
    const float* whp = w_hh + row * HID;
#pragma unroll
    for (int k = 0; k < HID; ++k) wh[g][k] = whp[k];
    bias[g] = b_ih[row] + b_hh[row];
  }
  __syncthreads();

  float h0, h1, c0, c1;
  if (t0 == 0) {
    h0 = h1 = c0 = c1 = 0.0f;
  } else {
    h0 = ws[ST_H1 + b0 * HID + lane];
    h1 = ws[ST_H1 + b1 * HID + lane];
    c0 = ws[ST_C1 + b0 * HID + lane];
    c1 = ws[ST_C1 + b1 * HID + lane];
  }

#pragma unroll 1
  for (int tt = 0; tt < Tc; ++tt) {
    const float yv0 = y0[((size_t)b0 * Tc + tt) * HID + lane];
    const float yv1 = y0[((size_t)b1 * Tc + tt) * HID + lane];

    float a0[4], a1[4];
#pragma unroll
    for (int g = 0; g < 4; ++g) { a0[g] = bias[g]; a1[g] = bias[g]; }

    // recurrent (register weights) first — hides the yv global-load latency
#pragma unroll
    for (int k = 0; k < HID; ++k) {
      const float hk0 = bcastf(h0, k);
      const float hk1 = bcastf(h1, k);
#pragma unroll
      for (int g = 0; g < 4; ++g) {
        a0[g] = fmaf(wh[g][k], hk0, a0[g]);
        a1[g] = fmaf(wh[g][k], hk1, a1[g]);
      }
    }

    // input part: W_ih1 from LDS, one b128 per k
#pragma unroll
    for (int k = 0; k < HID; ++k) {
      const float yk0 = bcastf(yv0, k);
      const float yk1 = bcastf(yv1, k);
      const float4 wv = *(const float4*)&wlds[(k * 64 + lane) * 4];
      a0[0] = fmaf(wv.x, yk0, a0[0]);
      a0[1] = fmaf(wv.y, yk0, a0[1]);
      a0[2] = fmaf(wv.z, yk0, a0[2]);
      a0[3] = fmaf(wv.w, yk0, a0[3]);
      a1[0] = fmaf(wv.x, yk1, a1[0]);
      a1[1] = fmaf(wv.y, yk1, a1[1]);
      a1[2] = fmaf(wv.z, yk1, a1[2]);
      a1[3] = fmaf(wv.w, yk1, a1[3]);
    }

    {
      const float ig = sigm(a0[0]), fg = sigm(a0[1]), gv = ftanh(a0[2]), og = sigm(a0[3]);
      c0 = fg * c0 + ig * gv;
      h0 = og * ftanh(c0);
    }
    {
      const float ig = sigm(a1[0]), fg = sigm(a1[1]), gv = ftanh(a1[2]), og = sigm(a1[3]);
      c1 = fg * c1 + ig * gv;
      h1 = og * ftanh(c1);
    }
  }

  ws[ST_H1 + b0 * HID + lane] = h0;
  ws[ST_H1 + b1 * HID + lane] = h1;
  ws[ST_C1 + b0 * HID + lane] = c0;
  ws[ST_C1 + b1 * HID + lane] = c1;

  if (t0 + Tc == T_SEQ) {
#pragma unroll
    for (int r = 0; r < 2; ++r) {
      const float hv = r ? h1 : h0;
      const int b = r ? b1 : b0;
#pragma unroll
      for (int j = 0; j < 5; ++j) {
        float p = w_out[j * HID + lane] * hv;
#pragma unroll
        for (int m = 32; m >= 1; m >>= 1) p += __shfl_xor(p, m, 64);
        if (lane == 0) out[b * 5 + j] = p + b_out[j];
      }
    }
  }
}

extern "C" void kernel_launch(void* const* d_in, const int* in_sizes, int n_in,
                              void* d_out, int out_size, void* d_ws, size_t ws_size,
                              hipStream_t stream) {
  const float* x = (const float*)d_in[0];
  const float* w_ih0 = (const float*)d_in[1];
  const float* w_hh0 = (const float*)d_in[2];
  const float* b_ih0 = (const float*)d_in[3];
  const float* b_hh0 = (const float*)d_in[4];
  const float* w_ih1 = (const float*)d_in[5];
  const float* w_hh1 = (const float*)d_in[6];
  const float* b_ih1 = (const float*)d_in[7];
  const float* b_hh1 = (const float*)d_in[8];
  const float* w_out = (const float*)d_in[9];
  const float* b_out = (const float*)d_in[10];
  float* out = (float*)d_out;
  float* ws = (float*)d_ws;

  // pick largest power-of-2 time chunk whose y0 buffer fits the workspace
  const size_t avail = ws_size / sizeof(float);
  int Tc = T_SEQ;
  while (Tc > 1 && (size_t)Y0_OFF + (size_t)NBATCH * Tc * HID > avail) Tc >>= 1;

  for (int t0 = 0; t0 < T_SEQ; t0 += Tc) {
    hipLaunchKernelGGL(lstm_layer0, dim3(NBATCH / 8), dim3(256), 0, stream,
                       x, w_ih0, w_hh0, b_ih0, b_hh0, ws, t0, Tc);
    hipLaunchKernelGGL(lstm_layer1, dim3(NBATCH / 8), dim3(256), 0, stream,
                       w_ih1, w_hh1, b_ih1, b_hh1, w_out, b_out, out, ws, t0, Tc);
  }
}

// Round 2
// 4066.532 us; speedup vs baseline: 7.2197x; 7.2197x over previous
//
#include <hip/hip_runtime.h>

#define T_SEQ 512
#define NBATCH 2048
#define HID 64
#define NIN 20
#define OUT_N 5
#define R 4     // batches per block; R*HID must == 256
#define XT 32   // x timesteps staged in LDS per refill

__device__ __forceinline__ float sigm(float v) {
  return __builtin_amdgcn_rcpf(1.0f + __expf(-v));
}
__device__ __forceinline__ float ftanh(float v) {
  const float a = fabsf(v);
  const float e = __expf(-2.0f * a);
  const float r = (1.0f - e) * __builtin_amdgcn_rcpf(1.0f + e);
  return copysignf(r, v);
}

// Fused 2-layer LSTM + projection. Block = 256 threads = 4 waves; wave g owns
// gate g (rows g*64..g*64+63 of each weight matrix) -> 212 weight floats/lane,
// fits in arch VGPRs (no spill). R=4 batches per block; h0/h1 broadcast via
// LDS uniform float4 reads (LDS pipe, not VALU). c kept in the update-thread's
// registers (thread tid owns pair (b=tid>>6, u=tid&63)).
__global__ __launch_bounds__(256, 2) void lstm_fused(
    const float* __restrict__ x,
    const float* __restrict__ w_ih0, const float* __restrict__ w_hh0,
    const float* __restrict__ b_ih0, const float* __restrict__ b_hh0,
    const float* __restrict__ w_ih1, const float* __restrict__ w_hh1,
    const float* __restrict__ b_ih1, const float* __restrict__ b_hh1,
    const float* __restrict__ w_out, const float* __restrict__ b_out,
    float* __restrict__ out) {
  __shared__ float sh_h0[R * HID];       // layer0 hidden (also layer1 input)
  __shared__ float sh_h1[R * HID];       // layer1 hidden
  __shared__ float sh_g[4 * R * HID];    // gates [g][b][u]
  __shared__ float sh_x[R * XT * NIN];   // staged x chunk [b][tt][k]

  const int tid = threadIdx.x;
  const int lane = tid & 63;
  const int g = tid >> 6;  // wave id == gate id (PyTorch order i,f,g,o)
  const int bbase = blockIdx.x * R;
  const int row = g * HID + lane;

  // ---- register-resident weights (per-lane row of each matrix) ----
  float wi0[NIN], wh0[HID], wi1[HID], wh1[HID];
  {
    const float* p = w_ih0 + row * NIN;
#pragma unroll
    for (int k = 0; k < NIN; ++k) wi0[k] = p[k];
  }
  {
    const float* p = w_hh0 + row * HID;
#pragma unroll
    for (int k = 0; k < HID; ++k) wh0[k] = p[k];
  }
  {
    const float* p = w_ih1 + row * HID;
#pragma unroll
    for (int k = 0; k < HID; ++k) wi1[k] = p[k];
  }
  {
    const float* p = w_hh1 + row * HID;
#pragma unroll
    for (int k = 0; k < HID; ++k) wh1[k] = p[k];
  }
  const float bias0 = b_ih0[row] + b_hh0[row];
  const float bias1 = b_ih1[row] + b_hh1[row];

  // ---- state: h in LDS (needs broadcast), c in update-thread registers ----
  float c0 = 0.0f, c1 = 0.0f;
  sh_h0[tid] = 0.0f;  // R*HID == 256 == blockDim
  sh_h1[tid] = 0.0f;
  __syncthreads();

#pragma unroll 1
  for (int t = 0; t < T_SEQ; ++t) {
    // ---- stage x chunk (block-uniform condition; coalesced global loads) ----
    if ((t & (XT - 1)) == 0) {
      __syncthreads();  // protect sh_x against readers from previous chunk
#pragma unroll
      for (int i = 0; i < (R * XT * NIN) / 256; ++i) {
        const int e = i * 256 + tid;
        const int b = e / (XT * NIN);
        const int r = e - b * (XT * NIN);
        sh_x[e] = x[((size_t)(bbase + b) * T_SEQ + t) * NIN + r];
      }
      __syncthreads();
    }
    const int tt = t & (XT - 1);

    // ================= layer 0 gates =================
    {
      float acc[R];
#pragma unroll
      for (int b = 0; b < R; ++b) {
        float a = bias0;
        const float4* xp = (const float4*)&sh_x[(b * XT + tt) * NIN];
        const float4* hp = (const float4*)&sh_h0[b * HID];
#pragma unroll
        for (int k4 = 0; k4 < NIN / 4; ++k4) {
          const float4 v = xp[k4];  // uniform-address broadcast read
          a = fmaf(wi0[4 * k4 + 0], v.x, a);
          a = fmaf(wi0[4 * k4 + 1], v.y, a);
          a = fmaf(wi0[4 * k4 + 2], v.z, a);
          a = fmaf(wi0[4 * k4 + 3], v.w, a);
        }
#pragma unroll
        for (int k4 = 0; k4 < HID / 4; ++k4) {
          const float4 v = hp[k4];
          a = fmaf(wh0[4 * k4 + 0], v.x, a);
          a = fmaf(wh0[4 * k4 + 1], v.y, a);
          a = fmaf(wh0[4 * k4 + 2], v.z, a);
          a = fmaf(wh0[4 * k4 + 3], v.w, a);
        }
        acc[b] = a;
      }
#pragma unroll
      for (int b = 0; b < R; ++b) sh_g[(g * R + b) * HID + lane] = acc[b];
    }
    __syncthreads();

    // ---- layer 0 pointwise update: thread tid owns (b,u) pair tid ----
    {
      const float iv = sigm(sh_g[0 * R * HID + tid]);
      const float fv = sigm(sh_g[1 * R * HID + tid]);
      const float gv = ftanh(sh_g[2 * R * HID + tid]);
      const float ov = sigm(sh_g[3 * R * HID + tid]);
      c0 = fv * c0 + iv * gv;
      sh_h0[tid] = ov * ftanh(c0);  // h0(t) — layer1's input y0(t)
    }
    __syncthreads();

    // ================= layer 1 gates =================
    {
      float acc[R];
#pragma unroll
      for (int b = 0; b < R; ++b) {
        float a = bias1;
        const float4* yp = (const float4*)&sh_h0[b * HID];  // post-update h0(t)
        const float4* hp = (const float4*)&sh_h1[b * HID];  // h1(t-1)
#pragma unroll
        for (int k4 = 0; k4 < HID / 4; ++k4) {
          const float4 v = yp[k4];
          a = fmaf(wi1[4 * k4 + 0], v.x, a);
          a = fmaf(wi1[4 * k4 + 1], v.y, a);
          a = fmaf(wi1[4 * k4 + 2], v.z, a);
          a = fmaf(wi1[4 * k4 + 3], v.w, a);
        }
#pragma unroll
        for (int k4 = 0; k4 < HID / 4; ++k4) {
          const float4 v = hp[k4];
          a = fmaf(wh1[4 * k4 + 0], v.x, a);
          a = fmaf(wh1[4 * k4 + 1], v.y, a);
          a = fmaf(wh1[4 * k4 + 2], v.z, a);
          a = fmaf(wh1[4 * k4 + 3], v.w, a);
        }
        acc[b] = a;
      }
#pragma unroll
      for (int b = 0; b < R; ++b) sh_g[(g * R + b) * HID + lane] = acc[b];
    }
    __syncthreads();

    // ---- layer 1 pointwise update ----
    {
      const float iv = sigm(sh_g[0 * R * HID + tid]);
      const float fv = sigm(sh_g[1 * R * HID + tid]);
      const float gv = ftanh(sh_g[2 * R * HID + tid]);
      const float ov = sigm(sh_g[3 * R * HID + tid]);
      c1 = fv * c1 + iv * gv;
      sh_h1[tid] = ov * ftanh(c1);
    }
    __syncthreads();
  }

  // ---- fused projection: out[b] = h1 @ w_out^T + b_out ----
  if (tid < R * OUT_N) {
    const int b = tid / OUT_N;
    const int j = tid - b * OUT_N;
    float p = b_out[j];
#pragma unroll
    for (int u = 0; u < HID; ++u) p = fmaf(w_out[j * HID + u], sh_h1[b * HID + u], p);
    out[(size_t)(bbase + b) * OUT_N + j] = p;
  }
}

extern "C" void kernel_launch(void* const* d_in, const int* in_sizes, int n_in,
                              void* d_out, int out_size, void* d_ws, size_t ws_size,
                              hipStream_t stream) {
  const float* x = (const float*)d_in[0];
  const float* w_ih0 = (const float*)d_in[1];
  const float* w_hh0 = (const float*)d_in[2];
  const float* b_ih0 = (const float*)d_in[3];
  const float* b_hh0 = (const float*)d_in[4];
  const float* w_ih1 = (const float*)d_in[5];
  const float* w_hh1 = (const float*)d_in[6];
  const float* b_ih1 = (const float*)d_in[7];
  const float* b_hh1 = (const float*)d_in[8];
  const float* w_out = (const float*)d_in[9];
  const float* b_out = (const float*)d_in[10];
  float* out = (float*)d_out;

  hipLaunchKernelGGL(lstm_fused, dim3(NBATCH / R), dim3(256), 0, stream,
                     x, w_ih0, w_hh0, b_ih0, b_hh0,
                     w_ih1, w_hh1, b_ih1, b_hh1, w_out, b_out, out);
}

// Round 3
// 3835.577 us; speedup vs baseline: 7.6544x; 1.0602x over previous
//
#include <hip/hip_runtime.h>

#define T_SEQ 512
#define NBATCH 2048
#define HID 64
#define NIN 20
#define OUT_N 5
#define R 4     // batches per block
#define XT 32   // x timesteps staged in LDS per refill

__device__ __forceinline__ float rlane(float v, int k) {
  return __uint_as_float((unsigned)__builtin_amdgcn_readlane((int)__float_as_uint(v), k));
}
__device__ __forceinline__ float sigm(float v) {
  return __builtin_amdgcn_rcpf(1.0f + __expf(-v));
}
__device__ __forceinline__ float ftanh(float v) {
  const float a = fabsf(v);
  const float e = __expf(-2.0f * a);
  return copysignf((1.0f - e) * __builtin_amdgcn_rcpf(1.0f + e), v);
}

// Fused 2-layer LSTM + projection, readlane-broadcast version.
// Block = 4 waves; wave g owns gate g's 64 rows (weights: 212 VGPR/lane).
// h/c state is REPLICATED per wave (lane u holds h,c of unit u for all R
// batches) so the k-dot-product broadcast is v_readlane -> SGPR -> FMA
// (VALU pipe) instead of LDS b128 broadcasts (which over-subscribed the
// shared LDS pipe 4:1 in R2). Gates cross the wave boundary once per layer
// via conflict-free b32 LDS; x stays as LDS b128 broadcast (small).
__global__ __launch_bounds__(256, 2) void lstm_fused(
    const float* __restrict__ x,
    const float* __restrict__ w_ih0, const float* __restrict__ w_hh0,
    const float* __restrict__ b_ih0, const float* __restrict__ b_hh0,
    const float* __restrict__ w_ih1, const float* __restrict__ w_hh1,
    const float* __restrict__ b_ih1, const float* __restrict__ b_hh1,
    const float* __restrict__ w_out, const float* __restrict__ b_out,
    float* __restrict__ out) {
  __shared__ float sh_x[R * XT * NIN];   // [b][tt][k]
  __shared__ float sh_gA[R * 4 * HID];   // layer0 gates [b][g][u]
  __shared__ float sh_gB[R * 4 * HID];   // layer1 gates [b][g][u]

  const int tid = threadIdx.x;
  const int lane = tid & 63;
  const int g = tid >> 6;  // wave id == gate id (i,f,g,o)
  const int bbase = blockIdx.x * R;
  const int row = g * HID + lane;

  // ---- register-resident weights: this wave's gate rows ----
  float wi0[NIN], wh0[HID], wi1[HID], wh1[HID];
  {
    const float* p = w_ih0 + row * NIN;
#pragma unroll
    for (int k = 0; k < NIN; ++k) wi0[k] = p[k];
  }
  {
    const float* p = w_hh0 + row * HID;
#pragma unroll
    for (int k = 0; k < HID; ++k) wh0[k] = p[k];
  }
  {
    const float* p = w_ih1 + row * HID;
#pragma unroll
    for (int k = 0; k < HID; ++k) wi1[k] = p[k];
  }
  {
    const float* p = w_hh1 + row * HID;
#pragma unroll
    for (int k = 0; k < HID; ++k) wh1[k] = p[k];
  }
  const float bias0 = b_ih0[row] + b_hh0[row];
  const float bias1 = b_ih1[row] + b_hh1[row];

  // ---- replicated state: lane u holds (h,c) of unit u for R batches ----
  float h0r[R], c0r[R], h1r[R], c1r[R];
#pragma unroll
  for (int b = 0; b < R; ++b) h0r[b] = c0r[b] = h1r[b] = c1r[b] = 0.0f;

#pragma unroll 1
  for (int t = 0; t < T_SEQ; ++t) {
    // ---- stage x chunk (coalesced; previous chunk's readers are already
    // past barrier A of t-1, so only a post-write barrier is needed) ----
    if ((t & (XT - 1)) == 0) {
#pragma unroll
      for (int i = 0; i < (R * XT * NIN) / 256; ++i) {
        const int e = i * 256 + tid;
        const int b = e / (XT * NIN);
        const int r = e - b * (XT * NIN);
        sh_x[e] = x[((size_t)(bbase + b) * T_SEQ + t) * NIN + r];
      }
      __syncthreads();
    }
    const int tt = t & (XT - 1);

    // ================= layer 0 gates =================
    {
      float a[R];
#pragma unroll
      for (int b = 0; b < R; ++b) a[b] = bias0;
      // h part: readlane broadcast (VALU), 4 independent chains
#pragma unroll
      for (int k = 0; k < HID; ++k) {
#pragma unroll
        for (int b = 0; b < R; ++b) a[b] = fmaf(wh0[k], rlane(h0r[b], k), a[b]);
      }
      // x part: LDS b128 broadcast (only 5 reads per batch)
#pragma unroll
      for (int b = 0; b < R; ++b) {
        const float4* xp = (const float4*)&sh_x[(b * XT + tt) * NIN];
#pragma unroll
        for (int k4 = 0; k4 < NIN / 4; ++k4) {
          const float4 v = xp[k4];
          a[b] = fmaf(wi0[4 * k4 + 0], v.x, a[b]);
          a[b] = fmaf(wi0[4 * k4 + 1], v.y, a[b]);
          a[b] = fmaf(wi0[4 * k4 + 2], v.z, a[b]);
          a[b] = fmaf(wi0[4 * k4 + 3], v.w, a[b]);
        }
      }
#pragma unroll
      for (int b = 0; b < R; ++b) sh_gA[(b * 4 + g) * HID + lane] = a[b];
    }
    __syncthreads();  // barrier A

    // ---- layer0 pointwise, replicated in every wave (unit = lane) ----
#pragma unroll
    for (int b = 0; b < R; ++b) {
      const float iv = sigm(sh_gA[(b * 4 + 0) * HID + lane]);
      const float fv = sigm(sh_gA[(b * 4 + 1) * HID + lane]);
      const float gv = ftanh(sh_gA[(b * 4 + 2) * HID + lane]);
      const float ov = sigm(sh_gA[(b * 4 + 3) * HID + lane]);
      c0r[b] = fv * c0r[b] + iv * gv;
      h0r[b] = ov * ftanh(c0r[b]);
    }

    // ================= layer 1 gates =================
    {
      float a[R];
#pragma unroll
      for (int b = 0; b < R; ++b) a[b] = bias1;
#pragma unroll
      for (int k = 0; k < HID; ++k) {
#pragma unroll
        for (int b = 0; b < R; ++b) {
          a[b] = fmaf(wi1[k], rlane(h0r[b], k), a[b]);  // input = h0(t)
          a[b] = fmaf(wh1[k], rlane(h1r[b], k), a[b]);  // recurrent h1(t-1)
        }
      }
#pragma unroll
      for (int b = 0; b < R; ++b) sh_gB[(b * 4 + g) * HID + lane] = a[b];
    }
    __syncthreads();  // barrier B

    // ---- layer1 pointwise, replicated ----
#pragma unroll
    for (int b = 0; b < R; ++b) {
      const float iv = sigm(sh_gB[(b * 4 + 0) * HID + lane]);
      const float fv = sigm(sh_gB[(b * 4 + 1) * HID + lane]);
      const float gv = ftanh(sh_gB[(b * 4 + 2) * HID + lane]);
      const float ov = sigm(sh_gB[(b * 4 + 3) * HID + lane]);
      c1r[b] = fv * c1r[b] + iv * gv;
      h1r[b] = ov * ftanh(c1r[b]);
    }
  }

  // ---- fused projection: out[b] = h1 @ w_out^T + b_out (wave 0 only) ----
  if (g == 0) {
#pragma unroll
    for (int b = 0; b < R; ++b) {
#pragma unroll
      for (int j = 0; j < OUT_N; ++j) {
        float p = w_out[j * HID + lane] * h1r[b];
#pragma unroll
        for (int m = 32; m >= 1; m >>= 1) p += __shfl_xor(p, m, 64);
        if (lane == 0) out[(size_t)(bbase + b) * OUT_N + j] = p + b_out[j];
      }
    }
  }
}

extern "C" void kernel_launch(void* const* d_in, const int* in_sizes, int n_in,
                              void* d_out, int out_size, void* d_ws, size_t ws_size,
                              hipStream_t stream) {
  const float* x = (const float*)d_in[0];
  const float* w_ih0 = (const float*)d_in[1];
  const float* w_hh0 = (const float*)d_in[2];
  const float* b_ih0 = (const float*)d_in[3];
  const float* b_hh0 = (const float*)d_in[4];
  const float* w_ih1 = (const float*)d_in[5];
  const float* w_hh1 = (const float*)d_in[6];
  const float* b_ih1 = (const float*)d_in[7];
  const float* b_hh1 = (const float*)d_in[8];
  const float* w_out = (const float*)d_in[9];
  const float* b_out = (const float*)d_in[10];
  float* out = (float*)d_out;

  hipLaunchKernelGGL(lstm_fused, dim3(NBATCH / R), dim3(256), 0, stream,
                     x, w_ih0, w_hh0, b_ih0, b_hh0,
                     w_ih1, w_hh1, b_ih1, b_hh1, w_out, b_out, out);
}